// Round 9
// baseline (242.920 us; speedup 1.0000x reference)
//
#include <hip/hip_runtime.h>
#include <hip/hip_bf16.h>
#include <stdint.h>

#define M_DIM 8192
#define N_DIM 4096
#define K_DIM 4096

typedef __attribute__((ext_vector_type(4))) int   int4v;
typedef __attribute__((ext_vector_type(4))) float floatx4;

// ---------------- pre-pass 1: per-row quantize x f32 -> i8, scale = rowmax/127 -------
__global__ __launch_bounds__(256) void quant_x_kernel(const float* __restrict__ x,
                                                      signed char* __restrict__ xq,
                                                      float* __restrict__ xs) {
    const int row = blockIdx.x;
    const int tid = threadIdx.x;
    const int wave = tid >> 6, lane = tid & 63;
    const float4* xr = (const float4*)(x + (size_t)row * K_DIM);

    float4 v[4];
    float m = 0.f;
    #pragma unroll
    for (int j = 0; j < 4; ++j) {
        v[j] = xr[j * 256 + tid];
        m = fmaxf(m, fmaxf(fmaxf(fabsf(v[j].x), fabsf(v[j].y)),
                           fmaxf(fabsf(v[j].z), fabsf(v[j].w))));
    }
    #pragma unroll
    for (int off = 32; off >= 1; off >>= 1) m = fmaxf(m, __shfl_down(m, off));
    __shared__ float wm[4];
    if (lane == 0) wm[wave] = m;
    __syncthreads();
    const float M = fmaxf(fmaxf(wm[0], wm[1]), fmaxf(wm[2], wm[3]));
    const float inv = M > 0.f ? 127.f / M : 0.f;
    if (tid == 0) xs[row] = M > 0.f ? M / 127.f : 0.f;

    char4* xo = (char4*)(xq + (size_t)row * K_DIM);
    #pragma unroll
    for (int j = 0; j < 4; ++j) {
        char4 q;
        q.x = (signed char)__float2int_rn(v[j].x * inv);
        q.y = (signed char)__float2int_rn(v[j].y * inv);
        q.z = (signed char)__float2int_rn(v[j].z * inv);
        q.w = (signed char)__float2int_rn(v[j].w * inv);
        xo[j * 256 + tid] = q;
    }
}

// ------- pre-pass 2: w f32 [K][N] -> sign(w) i8 transposed [N][K] (LDS transpose) ----
__global__ __launch_bounds__(256) void cvt_w_kernel(const float* __restrict__ w,
                                                    signed char* __restrict__ wT) {
    __shared__ signed char tile[64][68];   // pad breaks pow2 column-read stride
    const int t  = threadIdx.x;
    const int k0 = blockIdx.y * 64;
    const int n0 = blockIdx.x * 64;
    #pragma unroll
    for (int p = 0; p < 4; ++p) {
        int kk = p * 16 + (t >> 4);
        int nn = (t & 15) * 4;
        float4 v = *reinterpret_cast<const float4*>(&w[(size_t)(k0 + kk) * N_DIM + n0 + nn]);
        tile[kk][nn + 0] = v.x > 0.f ? 1 : (v.x < 0.f ? -1 : 0);
        tile[kk][nn + 1] = v.y > 0.f ? 1 : (v.y < 0.f ? -1 : 0);
        tile[kk][nn + 2] = v.z > 0.f ? 1 : (v.z < 0.f ? -1 : 0);
        tile[kk][nn + 3] = v.w > 0.f ? 1 : (v.w < 0.f ? -1 : 0);
    }
    __syncthreads();
    const int r = t >> 2;          // local n row
    const int c = (t & 3) * 16;    // local k byte
    int4v o;
    signed char* op = (signed char*)&o;
    #pragma unroll
    for (int j = 0; j < 16; ++j) op[j] = tile[c + j][r];
    *reinterpret_cast<int4v*>(&wT[(size_t)(n0 + r) * K_DIM + k0 + c]) = o;
}

// =====================================================================================
// 256x256 i8 GEMM, B DIRECT-TO-REGISTER (no B in LDS):
//   C = relu( xs[row] * (Xq * signW^T) + bias )
// A: gload_lds-staged, As[2][2][128*64] (32 KiB), XOR swizzle f(row)=((row>>1)&3)<<4.
// B: each wave loads its 64x64 slice straight to VGPRs (4x int4v per lane), 2 tiles
//    ahead, into named double-buffer slots bA/bB (K-loop unrolled x2 -> static index).
//    Lane addr: BT[bn + wn*64 + nf*16 + (lane&15)][kt + (lane>>4)*16]  (64-B lines).
// Per tile: 8 ds_reads (a,a2) ; 2 A-GLD (t+1) ; 32 MFMA ; 4 b-loads (t+2) ;
//           vmcnt(4) ; barrier.
// vmcnt ledger: outstanding at tile end = [b(t+1)x4][A(t+1)x2][b(t+2)x4]=10;
// vmcnt(4) retires b(t+1)+A(t+1), keeps b(t+2). Prologue {A(0),b(0),b(1)} + vmcnt(4)
// establishes the same invariant. Compiler inserts counted waits for b-reg uses.
// =====================================================================================
#define BM 256
#define BN 256
#define BK 64
#define NT (K_DIM / BK)

#define GLD(gsrc, ldst) __builtin_amdgcn_global_load_lds( \
    (const __attribute__((address_space(1))) unsigned int*)(gsrc), \
    (__attribute__((address_space(3))) unsigned int*)(ldst), 16, 0, 0)

__global__ __launch_bounds__(512, 1) void gemm_i8_kernel(
    const signed char* __restrict__ A,   // [M][K] i8 (quantized x)
    const signed char* __restrict__ BT,  // [N][K] i8 = sign(w)^T
    const float* __restrict__ xsc,       // [M] row scales
    const float* __restrict__ bias,
    float* __restrict__ C)               // [M][N] f32
{
    __shared__ signed char As[2][2][128 * 64];   // 32 KiB total

    const int tid  = threadIdx.x;
    const int wave = tid >> 6;
    const int lane = tid & 63;
    const int wm   = wave >> 2;        // 0..1 : wave M-half
    const int wn   = wave & 3;         // 0..3 : wave N-slot

    // XCD-bijective swizzle (nwg = 512, divisible by 8)
    const int bid  = blockIdx.x;
    const int sbid = (bid & 7) * 64 + (bid >> 3);
    const int tn   = sbid & 15;
    const int tm   = sbid >> 4;
    const int bm   = tm * BM;
    const int bn   = tn * BN;

    // A staging (write side of swizzle): dest linear o = tid*16; row = tid>>2;
    // source col = ((tid&3) ^ ((tid>>3)&3)) * 16
    const int srow = tid >> 2;
    const int scol = ((tid & 3) ^ ((tid >> 3) & 3)) * 16;

    // A fragment read offsets (read side of swizzle)
    const int laneRow = (lane & 15) * 64;
    const int colX = ((lane >> 4) * 16) ^ (((lane >> 1) & 3) << 4);

    // B direct-load lane base pointers (one per n-fragment)
    const signed char* bb[4];
    #pragma unroll
    for (int nf = 0; nf < 4; ++nf)
        bb[nf] = BT + (size_t)(bn + wn * 64 + nf * 16 + (lane & 15)) * K_DIM
                    + (lane >> 4) * 16;

    int4v acc[8][4] = {};
    int4v a[4], a2[4];
    int4v bA[4], bB[4];   // named B double-buffer (static indexing, rule #20)

#define STAGE_HALF(R0, KOFS, LDST) do { \
    GLD(A + (size_t)((R0) + srow) * K_DIM + (KOFS) + scol, (LDST) + wave * 1024); \
  } while (0)

#define LOAD_B(SLOT, KOFS) do { \
    SLOT[0] = *(const int4v*)(bb[0] + (KOFS)); \
    SLOT[1] = *(const int4v*)(bb[1] + (KOFS)); \
    SLOT[2] = *(const int4v*)(bb[2] + (KOFS)); \
    SLOT[3] = *(const int4v*)(bb[3] + (KOFS)); \
  } while (0)

    // ---- prologue: A(0) staged, b(0)->bA, b(1)->bB; retire A(0)+b(0), keep b(1) ----
    STAGE_HALF(bm,       0, As[0][0]);
    STAGE_HALF(bm + 128, 0, As[0][1]);
    LOAD_B(bA, 0);
    LOAD_B(bB, BK);
    asm volatile("s_waitcnt vmcnt(4)" ::: "memory");
    __builtin_amdgcn_s_barrier();

#define TILE_BODY(T, AR_IDX, AS_IDX, BCUR) do { \
    const char* Ar = (const char*)As[AR_IDX][wm]; \
    const int kA = ((T) + 1 < NT ? (T) + 1 : NT - 1) * BK; \
    const int kB = ((T) + 2 < NT ? (T) + 2 : NT - 1) * BK; \
    a[0]  = *(const int4v*)(Ar + (0*16)*64 + laneRow + colX); \
    a[1]  = *(const int4v*)(Ar + (1*16)*64 + laneRow + colX); \
    a[2]  = *(const int4v*)(Ar + (2*16)*64 + laneRow + colX); \
    a[3]  = *(const int4v*)(Ar + (3*16)*64 + laneRow + colX); \
    a2[0] = *(const int4v*)(Ar + ((64+0*16))*64 + laneRow + colX); \
    a2[1] = *(const int4v*)(Ar + ((64+1*16))*64 + laneRow + colX); \
    a2[2] = *(const int4v*)(Ar + ((64+2*16))*64 + laneRow + colX); \
    a2[3] = *(const int4v*)(Ar + ((64+3*16))*64 + laneRow + colX); \
    STAGE_HALF(bm,       kA, As[AS_IDX][0]); \
    STAGE_HALF(bm + 128, kA, As[AS_IDX][1]); \
    __builtin_amdgcn_s_setprio(1); \
    _Pragma("unroll") \
    for (int mf = 0; mf < 4; ++mf) \
        _Pragma("unroll") \
        for (int nf = 0; nf < 4; ++nf) \
            acc[mf][nf] = __builtin_amdgcn_mfma_i32_16x16x64_i8( \
                a[mf], BCUR[nf], acc[mf][nf], 0, 0, 0); \
    _Pragma("unroll") \
    for (int mf = 0; mf < 4; ++mf) \
        _Pragma("unroll") \
        for (int nf = 0; nf < 4; ++nf) \
            acc[4 + mf][nf] = __builtin_amdgcn_mfma_i32_16x16x64_i8( \
                a2[mf], BCUR[nf], acc[4 + mf][nf], 0, 0, 0); \
    __builtin_amdgcn_s_setprio(0); \
    LOAD_B(BCUR, kB); /* refill this slot for tile T+2 (WAR ok: MFMAs issued) */ \
    asm volatile("s_waitcnt vmcnt(4)" ::: "memory"); \
    __builtin_amdgcn_s_barrier(); \
  } while (0)

    for (int t = 0; t < NT; t += 2) {
        TILE_BODY(t,     0, 1, bA);
        TILE_BODY(t + 1, 1, 0, bB);
    }

    // ---- epilogue: dequant (per-row scale) + bias + relu, f32 store ----
    float bv[4];
    #pragma unroll
    for (int nf = 0; nf < 4; ++nf)
        bv[nf] = bias[bn + wn * 64 + nf * 16 + (lane & 15)];
    #pragma unroll
    for (int mf = 0; mf < 8; ++mf) {
        const int row0 = bm + wm * 128 + mf * 16 + (lane >> 4) * 4;
        float sr[4];
        #pragma unroll
        for (int r = 0; r < 4; ++r) sr[r] = xsc[row0 + r];
        #pragma unroll
        for (int nf = 0; nf < 4; ++nf) {
            const int col = bn + wn * 64 + nf * 16 + (lane & 15);
            float* cp = C + (size_t)row0 * N_DIM + col;
            #pragma unroll
            for (int r = 0; r < 4; ++r) {
                float v = (float)acc[mf][nf][r] * sr[r] + bv[nf];
                cp[(size_t)r * N_DIM] = v > 0.f ? v : 0.f;
            }
        }
    }
}

// ---------------- fallback (only if ws_size too small): naive tiled fp32 -------------
__global__ void naive_kernel(const float* __restrict__ x, const float* __restrict__ w,
                             const float* __restrict__ b, float* __restrict__ out) {
    __shared__ float xs[16][16];
    __shared__ float ws[16][17];
    const int row = blockIdx.y * 16 + threadIdx.y;
    const int col = blockIdx.x * 16 + threadIdx.x;
    float acc = 0.f;
    for (int k0 = 0; k0 < K_DIM; k0 += 16) {
        xs[threadIdx.y][threadIdx.x] = x[(size_t)row * K_DIM + k0 + threadIdx.x];
        float wv = w[(size_t)(k0 + threadIdx.y) * N_DIM + col];
        ws[threadIdx.y][threadIdx.x] = wv > 0.f ? 1.f : (wv < 0.f ? -1.f : 0.f);
        __syncthreads();
        #pragma unroll
        for (int kk = 0; kk < 16; ++kk) acc += xs[threadIdx.y][kk] * ws[kk][threadIdx.x];
        __syncthreads();
    }
    float v = acc + b[col];
    out[(size_t)row * N_DIM + col] = v > 0.f ? v : 0.f;
}

extern "C" void kernel_launch(void* const* d_in, const int* in_sizes, int n_in,
                              void* d_out, int out_size, void* d_ws, size_t ws_size,
                              hipStream_t stream) {
    const float* x = (const float*)d_in[0];
    const float* w = (const float*)d_in[1];
    const float* b = (const float*)d_in[2];
    float* out = (float*)d_out;

    const size_t xq_bytes = (size_t)M_DIM * K_DIM;                 // 32 MiB i8
    const size_t wT_bytes = (size_t)K_DIM * N_DIM;                 // 16 MiB i8
    const size_t xs_bytes = (size_t)M_DIM * sizeof(float);         // 32 KiB

    if (ws_size >= xq_bytes + wT_bytes + xs_bytes) {
        signed char* xq = (signed char*)d_ws;
        signed char* wT = (signed char*)((char*)d_ws + xq_bytes);
        float*       xs = (float*)((char*)d_ws + xq_bytes + wT_bytes);
        quant_x_kernel<<<M_DIM, 256, 0, stream>>>(x, xq, xs);
        cvt_w_kernel<<<dim3(N_DIM / 64, K_DIM / 64), 256, 0, stream>>>(w, wT);
        gemm_i8_kernel<<<(M_DIM / BM) * (N_DIM / BN), 512, 0, stream>>>(xq, wT, xs, b, out);
    } else {
        naive_kernel<<<dim3(N_DIM / 16, M_DIM / 16), dim3(16, 16), 0, stream>>>(x, w, b, out);
    }
}

// Round 10
// 200.001 us; speedup vs baseline: 1.2146x; 1.2146x over previous
//
#include <hip/hip_runtime.h>
#include <hip/hip_bf16.h>
#include <stdint.h>

#define M_DIM 8192
#define N_DIM 4096
#define K_DIM 4096

typedef __attribute__((ext_vector_type(4)))  int   int4v;
typedef __attribute__((ext_vector_type(16))) int   int16v;
typedef __attribute__((ext_vector_type(4)))  float floatx4;

// ---------------- pre-pass 1: per-row quantize x f32 -> i8, scale = rowmax/127 -------
__global__ __launch_bounds__(256) void quant_x_kernel(const float* __restrict__ x,
                                                      signed char* __restrict__ xq,
                                                      float* __restrict__ xs) {
    const int row = blockIdx.x;
    const int tid = threadIdx.x;
    const int wave = tid >> 6, lane = tid & 63;
    const float4* xr = (const float4*)(x + (size_t)row * K_DIM);

    float4 v[4];
    float m = 0.f;
    #pragma unroll
    for (int j = 0; j < 4; ++j) {
        v[j] = xr[j * 256 + tid];
        m = fmaxf(m, fmaxf(fmaxf(fabsf(v[j].x), fabsf(v[j].y)),
                           fmaxf(fabsf(v[j].z), fabsf(v[j].w))));
    }
    #pragma unroll
    for (int off = 32; off >= 1; off >>= 1) m = fmaxf(m, __shfl_down(m, off));
    __shared__ float wm[4];
    if (lane == 0) wm[wave] = m;
    __syncthreads();
    const float M = fmaxf(fmaxf(wm[0], wm[1]), fmaxf(wm[2], wm[3]));
    const float inv = M > 0.f ? 127.f / M : 0.f;
    if (tid == 0) xs[row] = M > 0.f ? M / 127.f : 0.f;

    char4* xo = (char4*)(xq + (size_t)row * K_DIM);
    #pragma unroll
    for (int j = 0; j < 4; ++j) {
        char4 q;
        q.x = (signed char)__float2int_rn(v[j].x * inv);
        q.y = (signed char)__float2int_rn(v[j].y * inv);
        q.z = (signed char)__float2int_rn(v[j].z * inv);
        q.w = (signed char)__float2int_rn(v[j].w * inv);
        xo[j * 256 + tid] = q;
    }
}

// ------- pre-pass 2: w f32 [K][N] -> sign(w) i8 transposed [N][K] (LDS transpose) ----
__global__ __launch_bounds__(256) void cvt_w_kernel(const float* __restrict__ w,
                                                    signed char* __restrict__ wT) {
    __shared__ signed char tile[64][68];   // pad breaks pow2 column-read stride
    const int t  = threadIdx.x;
    const int k0 = blockIdx.y * 64;
    const int n0 = blockIdx.x * 64;
    #pragma unroll
    for (int p = 0; p < 4; ++p) {
        int kk = p * 16 + (t >> 4);
        int nn = (t & 15) * 4;
        float4 v = *reinterpret_cast<const float4*>(&w[(size_t)(k0 + kk) * N_DIM + n0 + nn]);
        tile[kk][nn + 0] = v.x > 0.f ? 1 : (v.x < 0.f ? -1 : 0);
        tile[kk][nn + 1] = v.y > 0.f ? 1 : (v.y < 0.f ? -1 : 0);
        tile[kk][nn + 2] = v.z > 0.f ? 1 : (v.z < 0.f ? -1 : 0);
        tile[kk][nn + 3] = v.w > 0.f ? 1 : (v.w < 0.f ? -1 : 0);
    }
    __syncthreads();
    const int r = t >> 2;          // local n row
    const int c = (t & 3) * 16;    // local k byte
    int4v o;
    signed char* op = (signed char*)&o;
    #pragma unroll
    for (int j = 0; j < 16; ++j) op[j] = tile[c + j][r];
    *reinterpret_cast<int4v*>(&wT[(size_t)(n0 + r) * K_DIM + k0 + c]) = o;
}

// =====================================================================================
// 256x256 i8 GEMM, r7 schedule (2 barriers/K-tile, compiler-counted waits), MFMA shape
// switched to mfma_i32_32x32x32_i8 (rate 4404 vs 3944 TOPS, 16 instrs/tile vs 32):
//   C = relu( xs[row] * (Xq * signW^T) + bias )
// LDS halves [128 rows][64 k] i8, stored swizzle UNCHANGED: f(row)=((row>>1)&3)<<4.
// 32x32 operand read: row=lane&31, col=(ks*32 + (lane>>5)*16) ^ f(row bits2:1=lane bits2:1)
//   -> closed in bits 5:4, bank-counted 2 dwords/bank per quarter-wave (floor).
// C/D layout (m74/m101): col=lane&31, row=(reg&3)+8*(reg>>2)+4*(lane>>5).
// =====================================================================================
#define BM 256
#define BN 256
#define BK 64
#define NT (K_DIM / BK)

#define GLD(gsrc, ldst) __builtin_amdgcn_global_load_lds( \
    (const __attribute__((address_space(1))) unsigned int*)(gsrc), \
    (__attribute__((address_space(3))) unsigned int*)(ldst), 16, 0, 0)

__global__ __launch_bounds__(512, 2) void gemm_i8_kernel(
    const signed char* __restrict__ A,   // [M][K] i8 (quantized x)
    const signed char* __restrict__ BT,  // [N][K] i8 = sign(w)^T
    const float* __restrict__ xsc,       // [M] row scales
    const float* __restrict__ bias,
    float* __restrict__ C)               // [M][N] f32
{
    __shared__ signed char As[2][2][128 * 64];   // 32 KiB
    __shared__ signed char Bs[2][2][128 * 64];   // 32 KiB

    const int tid  = threadIdx.x;
    const int wave = tid >> 6;
    const int lane = tid & 63;
    const int wm   = wave >> 2;        // 0..1 : wave M-half (reads As[][wm], 128 rows)
    const int wn   = wave & 3;         // 0..3 : wave N-slot
    const int bh   = wn >> 1;          // B LDS half this wave reads
    const int brow0 = (wn & 1) * 64;   // row base inside that half

    // XCD-bijective swizzle (nwg = 512, divisible by 8)
    const int bid  = blockIdx.x;
    const int sbid = (bid & 7) * 64 + (bid >> 3);
    const int tn   = sbid & 15;
    const int tm   = sbid >> 4;
    const int bm   = tm * BM;
    const int bn   = tn * BN;

    // staging (write side of swizzle): dest linear o = tid*16; row = tid>>2;
    // source col = ((tid&3) ^ ((tid>>3)&3)) * 16
    const int srow = tid >> 2;
    const int scol = ((tid & 3) ^ ((tid >> 3) & 3)) * 16;

    // 32x32 fragment read offsets (read side of swizzle)
    const int laneRow = (lane & 31) * 64;
    const int fsw = ((lane >> 1) & 3) << 4;
    const int colX0 = (((lane >> 5) << 4) | 0)  ^ fsw;   // ks = 0
    const int colX1 = (((lane >> 5) << 4) | 32) ^ fsw;   // ks = 1

    int16v acc[4][2] = {};   // [mb][nb] : 4x2 blocks of 32x32 = 128 rows x 64 cols

#define STAGE_HALF(G, R0, KOFS, LDST) do { \
    GLD((G) + (size_t)((R0) + srow) * K_DIM + (KOFS) + scol, (LDST) + wave * 1024); \
  } while (0)

    // ---- prologue: tile0 {B0,B1,A0,A1}, tile1 {B0,B1}; drain tile0, keep (1).B ----
    STAGE_HALF(BT, bn,        0, Bs[0][0]);
    STAGE_HALF(BT, bn + 128,  0, Bs[0][1]);
    STAGE_HALF(A,  bm,        0, As[0][0]);
    STAGE_HALF(A,  bm + 128,  0, As[0][1]);
    STAGE_HALF(BT, bn,       BK, Bs[1][0]);
    STAGE_HALF(BT, bn + 128, BK, Bs[1][1]);
    asm volatile("s_waitcnt vmcnt(2)" ::: "memory");
    __builtin_amdgcn_s_barrier();

    int4v a[2][2];    // P1 A frags [mb 0-1][ks]
    int4v a2[2][2];   // P2 A frags [mb 2-3][ks]
    int4v b[2][2];    // B frags [nb][ks], live across the whole tile

    for (int t = 0; t < NT; ++t) {
        const int buf = t & 1;
        const char* Ar = (const char*)As[buf][wm];
        const char* Br = (const char*)Bs[buf][bh];
        const int kA = (t + 1 < NT ? t + 1 : NT - 1) * BK;   // tail reloads never read
        const int kB = (t + 2 < NT ? t + 2 : NT - 1) * BK;

        // ---- P1: mb 0-1 reads + all B + stage A(t+1) + 8 MFMA (counted waits) ----
        a[0][0] = *(const int4v*)(Ar + (0*32)*64 + laneRow + colX0);
        b[0][0] = *(const int4v*)(Br + (brow0 + 0*32)*64 + laneRow + colX0);
        b[0][1] = *(const int4v*)(Br + (brow0 + 0*32)*64 + laneRow + colX1);
        b[1][0] = *(const int4v*)(Br + (brow0 + 1*32)*64 + laneRow + colX0);
        b[1][1] = *(const int4v*)(Br + (brow0 + 1*32)*64 + laneRow + colX1);
        a[0][1] = *(const int4v*)(Ar + (0*32)*64 + laneRow + colX1);
        a[1][0] = *(const int4v*)(Ar + (1*32)*64 + laneRow + colX0);
        a[1][1] = *(const int4v*)(Ar + (1*32)*64 + laneRow + colX1);
        STAGE_HALF(A, bm,       kA, As[buf ^ 1][0]);
        STAGE_HALF(A, bm + 128, kA, As[buf ^ 1][1]);
        __builtin_amdgcn_s_setprio(1);
        #pragma unroll
        for (int mb = 0; mb < 2; ++mb)
            #pragma unroll
            for (int nb = 0; nb < 2; ++nb)
                #pragma unroll
                for (int ks = 0; ks < 2; ++ks)
                    acc[mb][nb] = __builtin_amdgcn_mfma_i32_32x32x32_i8(
                        a[mb][ks], b[nb][ks], acc[mb][nb], 0, 0, 0);
        __builtin_amdgcn_s_setprio(0);
        // MID barrier: every wave issued its P1 MFMAs => its a/b reads retired.
        __builtin_amdgcn_s_barrier();

        // ---- P2: mb 2-3 reads (As[buf], no writer this tile) + stage B(t+2) + 8 MFMA ----
        a2[0][0] = *(const int4v*)(Ar + (2*32)*64 + laneRow + colX0);
        a2[0][1] = *(const int4v*)(Ar + (2*32)*64 + laneRow + colX1);
        a2[1][0] = *(const int4v*)(Ar + (3*32)*64 + laneRow + colX0);
        a2[1][1] = *(const int4v*)(Ar + (3*32)*64 + laneRow + colX1);
        asm volatile("" ::: "memory");   // keep B-stage below the MID barrier
        STAGE_HALF(BT, bn,       kB, Bs[buf][0]);
        STAGE_HALF(BT, bn + 128, kB, Bs[buf][1]);
        __builtin_amdgcn_s_setprio(1);
        #pragma unroll
        for (int mb = 0; mb < 2; ++mb)
            #pragma unroll
            for (int nb = 0; nb < 2; ++nb)
                #pragma unroll
                for (int ks = 0; ks < 2; ++ks)
                    acc[2 + mb][nb] = __builtin_amdgcn_mfma_i32_32x32x32_i8(
                        a2[mb][ks], b[nb][ks], acc[2 + mb][nb], 0, 0, 0);
        __builtin_amdgcn_s_setprio(0);
        // drain A(t+1) (and older); keep only B(t+2)x2 in flight
        asm volatile("s_waitcnt vmcnt(2)" ::: "memory");
        __builtin_amdgcn_s_barrier();
    }

    // ---- epilogue: dequant (per-row scale) + bias + relu, f32 store ----
    // 32x32 C/D: col = lane&31, row = (reg&3) + 8*(reg>>2) + 4*(lane>>5)
    #pragma unroll
    for (int mb = 0; mb < 4; ++mb) {
        const int row0 = bm + wm * 128 + mb * 32 + 4 * (lane >> 5);
        float4 s[4];
        #pragma unroll
        for (int q = 0; q < 4; ++q)
            s[q] = *reinterpret_cast<const float4*>(&xsc[row0 + 8 * q]);
        #pragma unroll
        for (int nb = 0; nb < 2; ++nb) {
            const int col = bn + wn * 64 + nb * 32 + (lane & 31);
            const float bvv = bias[col];
            #pragma unroll
            for (int q = 0; q < 4; ++q)
                #pragma unroll
                for (int j = 0; j < 4; ++j) {
                    const int row = row0 + 8 * q + j;
                    float v = (float)acc[mb][nb][q * 4 + j] * ((const float*)&s[q])[j] + bvv;
                    C[(size_t)row * N_DIM + col] = v > 0.f ? v : 0.f;
                }
        }
    }
}

// ---------------- fallback (only if ws_size too small): naive tiled fp32 -------------
__global__ void naive_kernel(const float* __restrict__ x, const float* __restrict__ w,
                             const float* __restrict__ b, float* __restrict__ out) {
    __shared__ float xs[16][16];
    __shared__ float ws[16][17];
    const int row = blockIdx.y * 16 + threadIdx.y;
    const int col = blockIdx.x * 16 + threadIdx.x;
    float acc = 0.f;
    for (int k0 = 0; k0 < K_DIM; k0 += 16) {
        xs[threadIdx.y][threadIdx.x] = x[(size_t)row * K_DIM + k0 + threadIdx.x];
        float wv = w[(size_t)(k0 + threadIdx.y) * N_DIM + col];
        ws[threadIdx.y][threadIdx.x] = wv > 0.f ? 1.f : (wv < 0.f ? -1.f : 0.f);
        __syncthreads();
        #pragma unroll
        for (int kk = 0; kk < 16; ++kk) acc += xs[threadIdx.y][kk] * ws[kk][threadIdx.x];
        __syncthreads();
    }
    float v = acc + b[col];
    out[(size_t)row * N_DIM + col] = v > 0.f ? v : 0.f;
}

extern "C" void kernel_launch(void* const* d_in, const int* in_sizes, int n_in,
                              void* d_out, int out_size, void* d_ws, size_t ws_size,
                              hipStream_t stream) {
    const float* x = (const float*)d_in[0];
    const float* w = (const float*)d_in[1];
    const float* b = (const float*)d_in[2];
    float* out = (float*)d_out;

    const size_t xq_bytes = (size_t)M_DIM * K_DIM;                 // 32 MiB i8
    const size_t wT_bytes = (size_t)K_DIM * N_DIM;                 // 16 MiB i8
    const size_t xs_bytes = (size_t)M_DIM * sizeof(float);         // 32 KiB

    if (ws_size >= xq_bytes + wT_bytes + xs_bytes) {
        signed char* xq = (signed char*)d_ws;
        signed char* wT = (signed char*)((char*)d_ws + xq_bytes);
        float*       xs = (float*)((char*)d_ws + xq_bytes + wT_bytes);
        quant_x_kernel<<<M_DIM, 256, 0, stream>>>(x, xq, xs);
        cvt_w_kernel<<<dim3(N_DIM / 64, K_DIM / 64), 256, 0, stream>>>(w, wT);
        gemm_i8_kernel<<<(M_DIM / BM) * (N_DIM / BN), 512, 0, stream>>>(xq, wT, xs, b, out);
    } else {
        naive_kernel<<<dim3(N_DIM / 16, M_DIM / 16), dim3(16, 16), 0, stream>>>(x, w, b, out);
    }
}

// Round 11
// 183.015 us; speedup vs baseline: 1.3273x; 1.0928x over previous
//
#include <hip/hip_runtime.h>
#include <hip/hip_bf16.h>
#include <stdint.h>

#define M_DIM 8192
#define N_DIM 4096
#define K_DIM 4096

typedef __attribute__((ext_vector_type(4))) int   int4v;
typedef __attribute__((ext_vector_type(4))) float floatx4;

// ---------------- pre-pass 1: per-row quantize x f32 -> i8, scale = rowmax/127 -------
__global__ __launch_bounds__(256) void quant_x_kernel(const float* __restrict__ x,
                                                      signed char* __restrict__ xq,
                                                      float* __restrict__ xs) {
    const int row = blockIdx.x;
    const int tid = threadIdx.x;
    const int wave = tid >> 6, lane = tid & 63;
    const float4* xr = (const float4*)(x + (size_t)row * K_DIM);

    float4 v[4];
    float m = 0.f;
    #pragma unroll
    for (int j = 0; j < 4; ++j) {
        v[j] = xr[j * 256 + tid];
        m = fmaxf(m, fmaxf(fmaxf(fabsf(v[j].x), fabsf(v[j].y)),
                           fmaxf(fabsf(v[j].z), fabsf(v[j].w))));
    }
    #pragma unroll
    for (int off = 32; off >= 1; off >>= 1) m = fmaxf(m, __shfl_down(m, off));
    __shared__ float wm[4];
    if (lane == 0) wm[wave] = m;
    __syncthreads();
    const float M = fmaxf(fmaxf(wm[0], wm[1]), fmaxf(wm[2], wm[3]));
    const float inv = M > 0.f ? 127.f / M : 0.f;
    if (tid == 0) xs[row] = M > 0.f ? M / 127.f : 0.f;

    char4* xo = (char4*)(xq + (size_t)row * K_DIM);
    #pragma unroll
    for (int j = 0; j < 4; ++j) {
        char4 q;
        q.x = (signed char)__float2int_rn(v[j].x * inv);
        q.y = (signed char)__float2int_rn(v[j].y * inv);
        q.z = (signed char)__float2int_rn(v[j].z * inv);
        q.w = (signed char)__float2int_rn(v[j].w * inv);
        xo[j * 256 + tid] = q;
    }
}

// ------- pre-pass 2: w f32 [K][N] -> sign(w) i8 transposed [N][K] (LDS transpose) ----
__global__ __launch_bounds__(256) void cvt_w_kernel(const float* __restrict__ w,
                                                    signed char* __restrict__ wT) {
    __shared__ signed char tile[64][68];   // pad breaks pow2 column-read stride
    const int t  = threadIdx.x;
    const int k0 = blockIdx.y * 64;
    const int n0 = blockIdx.x * 64;
    #pragma unroll
    for (int p = 0; p < 4; ++p) {
        int kk = p * 16 + (t >> 4);
        int nn = (t & 15) * 4;
        float4 v = *reinterpret_cast<const float4*>(&w[(size_t)(k0 + kk) * N_DIM + n0 + nn]);
        tile[kk][nn + 0] = v.x > 0.f ? 1 : (v.x < 0.f ? -1 : 0);
        tile[kk][nn + 1] = v.y > 0.f ? 1 : (v.y < 0.f ? -1 : 0);
        tile[kk][nn + 2] = v.z > 0.f ? 1 : (v.z < 0.f ? -1 : 0);
        tile[kk][nn + 3] = v.w > 0.f ? 1 : (v.w < 0.f ? -1 : 0);
    }
    __syncthreads();
    const int r = t >> 2;          // local n row
    const int c = (t & 3) * 16;    // local k byte
    int4v o;
    signed char* op = (signed char*)&o;
    #pragma unroll
    for (int j = 0; j < 16; ++j) op[j] = tile[c + j][r];
    *reinterpret_cast<int4v*>(&wT[(size_t)(n0 + r) * K_DIM + k0 + c]) = o;
}

// =====================================================================================
// 256x256 i8 GEMM, triple-buffered A AND B, ONE barrier per K-tile, both operands
// staged TWO tiles ahead (tile-end vmcnt waits on loads issued a full tile earlier):
//   C = relu( xs[row] * (Xq * signW^T) + bias )
// Shape: mfma_i32_16x16x64_i8 (16-row frags are at the half-wave bank floor; 32-row
// frags 4-way conflict -- r10 measured). Swizzle f(row)=((row>>1)&3)<<4 (0-conflict).
// Per tile t: 12 ds_reads (slot t%3) ; stage A(t+2),B(t+2) -> slot (t+2)%3 (4 GLD) ;
//             32 MFMA (compiler counted lgkm waits) ; vmcnt(4) ; barrier.
// vmcnt ledger: outstanding at tile end = {A,B}(t+1)x4 (issued t-1) + {A,B}(t+2)x4
// (issued t) = 8; vmcnt(4) retires the t+1 pair -- issued ~2800 cyc ago, never stalls.
// Slot (t+2)%3 readers ran in tile t-1, sequenced by the end-(t-1) barrier.
// =====================================================================================
#define BM 256
#define BN 256
#define BK 64
#define NT (K_DIM / BK)

#define GLD(gsrc, ldst) __builtin_amdgcn_global_load_lds( \
    (const __attribute__((address_space(1))) unsigned int*)(gsrc), \
    (__attribute__((address_space(3))) unsigned int*)(ldst), 16, 0, 0)

__global__ __launch_bounds__(512, 2) void gemm_i8_kernel(
    const signed char* __restrict__ A,   // [M][K] i8 (quantized x)
    const signed char* __restrict__ BT,  // [N][K] i8 = sign(w)^T
    const float* __restrict__ xsc,       // [M] row scales
    const float* __restrict__ bias,
    float* __restrict__ C)               // [M][N] f32
{
    __shared__ signed char As[3][2][128 * 64];   // 48 KiB
    __shared__ signed char Bs[3][2][128 * 64];   // 48 KiB

    const int tid  = threadIdx.x;
    const int wave = tid >> 6;
    const int lane = tid & 63;
    const int wm   = wave >> 2;        // 0..1 : wave M-half
    const int wn   = wave & 3;         // 0..3 : wave N-slot
    const int bh   = wn >> 1;          // B LDS half this wave reads
    const int brow0 = (wn & 1) * 64;   // row base inside that half

    // XCD-bijective swizzle (nwg = 512, divisible by 8)
    const int bid  = blockIdx.x;
    const int sbid = (bid & 7) * 64 + (bid >> 3);
    const int tn   = sbid & 15;
    const int tm   = sbid >> 4;
    const int bm   = tm * BM;
    const int bn   = tn * BN;

    // staging (write side of swizzle): dest linear o = tid*16; row = tid>>2;
    // source col = ((tid&3) ^ ((tid>>3)&3)) * 16   [row bits 2:1 = tid bits 4:3]
    const int srow = tid >> 2;
    const int scol = ((tid & 3) ^ ((tid >> 3) & 3)) * 16;

    // fragment read offsets (read side of swizzle)
    const int laneRow = (lane & 15) * 64;
    const int colX = ((lane >> 4) * 16) ^ (((lane >> 1) & 3) << 4);

    int4v acc[8][4] = {};

#define STAGE_HALF(G, R0, KOFS, LDST) do { \
    GLD((G) + (size_t)((R0) + srow) * K_DIM + (KOFS) + scol, (LDST) + wave * 1024); \
  } while (0)

    // ---- prologue: {A(0),B(0)} then {A(1),B(1)}; retire tile0's 4, keep tile1's 4 ----
    STAGE_HALF(A,  bm,        0, As[0][0]);
    STAGE_HALF(A,  bm + 128,  0, As[0][1]);
    STAGE_HALF(BT, bn,        0, Bs[0][0]);
    STAGE_HALF(BT, bn + 128,  0, Bs[0][1]);
    STAGE_HALF(A,  bm,       BK, As[1][0]);
    STAGE_HALF(A,  bm + 128, BK, As[1][1]);
    STAGE_HALF(BT, bn,       BK, Bs[1][0]);
    STAGE_HALF(BT, bn + 128, BK, Bs[1][1]);
    asm volatile("s_waitcnt vmcnt(4)" ::: "memory");
    __builtin_amdgcn_s_barrier();

    int4v a[4];    // A frags rows 0-63 of wave half
    int4v a2[4];   // A frags rows 64-127
    int4v b[4];    // all 4 B n-frags

    int rd = 0;    // t % 3
    int st = 2;    // (t+2) % 3

    for (int t = 0; t < NT; ++t) {
        const char* Ar = (const char*)As[rd][wm];
        const char* Br = (const char*)Bs[rd][bh];
        const int kS = (t + 2 < NT ? t + 2 : NT - 1) * BK;   // tail reloads never read

        // ---- all 12 ds_reads, ordered to match MFMA consumption ----
        a[0]  = *(const int4v*)(Ar + (0*16)*64 + laneRow + colX);
        b[0]  = *(const int4v*)(Br + (brow0 +  0)*64 + laneRow + colX);
        b[1]  = *(const int4v*)(Br + (brow0 + 16)*64 + laneRow + colX);
        b[2]  = *(const int4v*)(Br + (brow0 + 32)*64 + laneRow + colX);
        b[3]  = *(const int4v*)(Br + (brow0 + 48)*64 + laneRow + colX);
        a[1]  = *(const int4v*)(Ar + (1*16)*64 + laneRow + colX);
        a[2]  = *(const int4v*)(Ar + (2*16)*64 + laneRow + colX);
        a[3]  = *(const int4v*)(Ar + (3*16)*64 + laneRow + colX);
        a2[0] = *(const int4v*)(Ar + ((64 + 0*16))*64 + laneRow + colX);
        a2[1] = *(const int4v*)(Ar + ((64 + 1*16))*64 + laneRow + colX);
        a2[2] = *(const int4v*)(Ar + ((64 + 2*16))*64 + laneRow + colX);
        a2[3] = *(const int4v*)(Ar + ((64 + 3*16))*64 + laneRow + colX);

        // ---- stage A(t+2), B(t+2) into slot (t+2)%3 (readers ran in tile t-1) ----
        STAGE_HALF(A,  bm,       kS, As[st][0]);
        STAGE_HALF(A,  bm + 128, kS, As[st][1]);
        STAGE_HALF(BT, bn,       kS, Bs[st][0]);
        STAGE_HALF(BT, bn + 128, kS, Bs[st][1]);

        // ---- 32 MFMA, one cluster (counted lgkm waits interleave reads) ----
        __builtin_amdgcn_s_setprio(1);
        #pragma unroll
        for (int mf = 0; mf < 4; ++mf)
            #pragma unroll
            for (int nf = 0; nf < 4; ++nf)
                acc[mf][nf] = __builtin_amdgcn_mfma_i32_16x16x64_i8(
                    a[mf], b[nf], acc[mf][nf], 0, 0, 0);
        #pragma unroll
        for (int mf = 0; mf < 4; ++mf)
            #pragma unroll
            for (int nf = 0; nf < 4; ++nf)
                acc[4 + mf][nf] = __builtin_amdgcn_mfma_i32_16x16x64_i8(
                    a2[mf], b[nf], acc[4 + mf][nf], 0, 0, 0);
        __builtin_amdgcn_s_setprio(0);

        // retire {A,B}(t+1) (issued a full tile ago); keep {A,B}(t+2) in flight
        asm volatile("s_waitcnt vmcnt(4)" ::: "memory");
        __builtin_amdgcn_s_barrier();

        rd = (rd == 2) ? 0 : rd + 1;
        st = (st == 2) ? 0 : st + 1;
    }

    // ---- epilogue: dequant (per-row scale) + bias + relu, f32 store ----
    float bv[4];
    #pragma unroll
    for (int nf = 0; nf < 4; ++nf)
        bv[nf] = bias[bn + wn * 64 + nf * 16 + (lane & 15)];
    #pragma unroll
    for (int mf = 0; mf < 8; ++mf) {
        const int row0 = bm + wm * 128 + mf * 16 + (lane >> 4) * 4;
        float sr[4];
        #pragma unroll
        for (int r = 0; r < 4; ++r) sr[r] = xsc[row0 + r];
        #pragma unroll
        for (int nf = 0; nf < 4; ++nf) {
            const int col = bn + wn * 64 + nf * 16 + (lane & 15);
            float* cp = C + (size_t)row0 * N_DIM + col;
            #pragma unroll
            for (int r = 0; r < 4; ++r) {
                float v = (float)acc[mf][nf][r] * sr[r] + bv[nf];
                cp[(size_t)r * N_DIM] = v > 0.f ? v : 0.f;
            }
        }
    }
}

// ---------------- fallback (only if ws_size too small): naive tiled fp32 -------------
__global__ void naive_kernel(const float* __restrict__ x, const float* __restrict__ w,
                             const float* __restrict__ b, float* __restrict__ out) {
    __shared__ float xs[16][16];
    __shared__ float ws[16][17];
    const int row = blockIdx.y * 16 + threadIdx.y;
    const int col = blockIdx.x * 16 + threadIdx.x;
    float acc = 0.f;
    for (int k0 = 0; k0 < K_DIM; k0 += 16) {
        xs[threadIdx.y][threadIdx.x] = x[(size_t)row * K_DIM + k0 + threadIdx.x];
        float wv = w[(size_t)(k0 + threadIdx.y) * N_DIM + col];
        ws[threadIdx.y][threadIdx.x] = wv > 0.f ? 1.f : (wv < 0.f ? -1.f : 0.f);
        __syncthreads();
        #pragma unroll
        for (int kk = 0; kk < 16; ++kk) acc += xs[threadIdx.y][kk] * ws[kk][threadIdx.x];
        __syncthreads();
    }
    float v = acc + b[col];
    out[(size_t)row * N_DIM + col] = v > 0.f ? v : 0.f;
}

extern "C" void kernel_launch(void* const* d_in, const int* in_sizes, int n_in,
                              void* d_out, int out_size, void* d_ws, size_t ws_size,
                              hipStream_t stream) {
    const float* x = (const float*)d_in[0];
    const float* w = (const float*)d_in[1];
    const float* b = (const float*)d_in[2];
    float* out = (float*)d_out;

    const size_t xq_bytes = (size_t)M_DIM * K_DIM;                 // 32 MiB i8
    const size_t wT_bytes = (size_t)K_DIM * N_DIM;                 // 16 MiB i8
    const size_t xs_bytes = (size_t)M_DIM * sizeof(float);         // 32 KiB

    if (ws_size >= xq_bytes + wT_bytes + xs_bytes) {
        signed char* xq = (signed char*)d_ws;
        signed char* wT = (signed char*)((char*)d_ws + xq_bytes);
        float*       xs = (float*)((char*)d_ws + xq_bytes + wT_bytes);
        quant_x_kernel<<<M_DIM, 256, 0, stream>>>(x, xq, xs);
        cvt_w_kernel<<<dim3(N_DIM / 64, K_DIM / 64), 256, 0, stream>>>(w, wT);
        gemm_i8_kernel<<<(M_DIM / BM) * (N_DIM / BN), 512, 0, stream>>>(xq, wT, xs, b, out);
    } else {
        naive_kernel<<<dim3(N_DIM / 16, M_DIM / 16), dim3(16, 16), 0, stream>>>(x, w, b, out);
    }
}